// Round 5
// baseline (309.772 us; speedup 1.0000x reference)
//
#include <hip/hip_runtime.h>
#include <math.h>

// Damping: B=32768, N=64, H=256, OFF=2016
//   diag: x -> tanh(Wd1) -> tanh(Wd2) -> Wdo   (64 per sample)
//   off : x -> tanh(Wo1) -> tanh(Wo2) -> Woo   (2016 per sample, strict lower tri)
//   out = L (L^T x0), L diag = xd, L[i][j](j<i) = z[i(i-1)/2+j]

#define B_TOT 32768
#define NDIM  64
#define HDIM  256
#define OFFD  2016
#define ZROW  2112  // packed tri rows, each padded to multiple of 4 (zero-filled)

typedef __bf16 bf16x8 __attribute__((ext_vector_type(8)));
typedef float  f32x4  __attribute__((ext_vector_type(4)));

__device__ __forceinline__ float fast_tanh(float x) {
  float e = __expf(2.f * x);
  return 1.f - 2.f * __builtin_amdgcn_rcpf(e + 1.f);
}
__device__ __forceinline__ float lane_bcast(float v, int l) {
  return __uint_as_float(__builtin_amdgcn_readlane(__float_as_uint(v), l));
}
__device__ __forceinline__ float bf_lo(unsigned w) { return __uint_as_float(w << 16); }
__device__ __forceinline__ float bf_hi(unsigned w) { return __uint_as_float(w & 0xffff0000u); }

// ---------------- weight cast (f32 -> bf16), single launch ----------------
__device__ __forceinline__ void cast_range(const float* __restrict__ s,
                                           __bf16* __restrict__ d, int n) {
  int i = blockIdx.x * blockDim.x + threadIdx.x;
  const int stride = gridDim.x * blockDim.x;
  for (; i < n; i += stride) d[i] = (__bf16)s[i];
}
__global__ __launch_bounds__(256) void cast_all_kernel(
    const float* s0, __bf16* d0, int n0, const float* s1, __bf16* d1, int n1,
    const float* s2, __bf16* d2, int n2, const float* s3, __bf16* d3, int n3,
    const float* s4, __bf16* d4, int n4, const float* s5, __bf16* d5, int n5) {
  cast_range(s0, d0, n0); cast_range(s1, d1, n1); cast_range(s2, d2, n2);
  cast_range(s3, d3, n3); cast_range(s4, d4, n4); cast_range(s5, d5, n5);
}

__device__ __forceinline__ bf16x8 cvt8(const float* __restrict__ p) {
  const float4 u = *(const float4*)p;
  const float4 v = *(const float4*)(p + 4);
  bf16x8 r;
  r[0] = (__bf16)u.x; r[1] = (__bf16)u.y; r[2] = (__bf16)u.z; r[3] = (__bf16)u.w;
  r[4] = (__bf16)v.x; r[5] = (__bf16)v.y; r[6] = (__bf16)v.z; r[7] = (__bf16)v.w;
  return r;
}

// ---------------- K1: both MLP trunks, 32 samples / WG, 8 waves ----------------
// chunked LDS: unit index = (ch>>3)*256 + s*8 + (ch&7); ch512 covers 512 channels
__global__ __launch_bounds__(512, 6) void trunk_kernel(
    const float* __restrict__ x, const __bf16* __restrict__ W1,
    const float* __restrict__ bd1, const float* __restrict__ bo1,
    const __bf16* __restrict__ Wd2, const float* __restrict__ bd2,
    const __bf16* __restrict__ Wdo, const float* __restrict__ bdo,
    const __bf16* __restrict__ Wo2, const float* __restrict__ bo2,
    __bf16* __restrict__ g2, float* __restrict__ xd) {
  __shared__ __bf16 ch512[64 * 256];  // 32 KB: h1 = chunks 0..31, g1 = chunks 32..63
  __shared__ __bf16 buf2[32 * 256];   // 16 KB: h2
  const int tid = threadIdx.x;
  const int wave = tid >> 6, lane = tid & 63;
  const int lr = lane & 15, lg = lane >> 4;
  const int sb = blockIdx.x * 32;

  // preload x A-fragments for all tiles (reused across every n)
  bf16x8 ax[2][2];
#pragma unroll
  for (int m = 0; m < 2; ++m)
#pragma unroll
    for (int ks = 0; ks < 2; ++ks)
      ax[m][ks] = cvt8(x + (size_t)(sb + m * 16 + lr) * NDIM + ks * 32 + lg * 8);

  // L1 (merged diag+off): 64 tiles (m2 x n32), K=64
  for (int u = 0; u < 8; ++u) {
    const int t = wave + 8 * u;
    const int m = t >> 5, n = t & 31;
    const int ch = n * 16 + lr;
    f32x4 acc = {0.f, 0.f, 0.f, 0.f};
#pragma unroll
    for (int ks = 0; ks < 2; ++ks) {
      bf16x8 b = *(const bf16x8*)(W1 + ch * NDIM + ks * 32 + lg * 8);
      acc = __builtin_amdgcn_mfma_f32_16x16x32_bf16(ax[m][ks], b, acc, 0, 0, 0);
    }
    const float bv = (ch < 256) ? bd1[ch] : bo1[ch - 256];
#pragma unroll
    for (int r = 0; r < 4; ++r) {
      const int s = m * 16 + lg * 4 + r;
      ch512[(ch >> 3) * 256 + s * 8 + (ch & 7)] = (__bf16)fast_tanh(acc[r] + bv);
    }
  }
  __syncthreads();

  // L2d: chunks 0..31 -> buf2 (tanh), K=256, 32 tiles (m2 x n16)
  for (int u = 0; u < 4; ++u) {
    const int t = wave + 8 * u;
    const int m = t >> 4, n = t & 15;
    const int ch = n * 16 + lr;
    f32x4 acc = {0.f, 0.f, 0.f, 0.f};
#pragma unroll
    for (int ks = 0; ks < 8; ++ks) {
      bf16x8 a = *(const bf16x8*)(ch512 + ((ks * 4 + lg) * 32 + m * 16 + lr) * 8);
      bf16x8 b = *(const bf16x8*)(Wd2 + ch * HDIM + ks * 32 + lg * 8);
      acc = __builtin_amdgcn_mfma_f32_16x16x32_bf16(a, b, acc, 0, 0, 0);
    }
    const float bv = bd2[ch];
#pragma unroll
    for (int r = 0; r < 4; ++r) {
      const int s = m * 16 + lg * 4 + r;
      buf2[(ch >> 3) * 256 + s * 8 + (ch & 7)] = (__bf16)fast_tanh(acc[r] + bv);
    }
  }
  // L2o: chunks 32..63 -> g2 global (tanh), K=256
  for (int u = 0; u < 4; ++u) {
    const int t = wave + 8 * u;
    const int m = t >> 4, n = t & 15;
    const int ch = n * 16 + lr;
    f32x4 acc = {0.f, 0.f, 0.f, 0.f};
#pragma unroll
    for (int ks = 0; ks < 8; ++ks) {
      bf16x8 a = *(const bf16x8*)(ch512 + ((32 + ks * 4 + lg) * 32 + m * 16 + lr) * 8);
      bf16x8 b = *(const bf16x8*)(Wo2 + ch * HDIM + ks * 32 + lg * 8);
      acc = __builtin_amdgcn_mfma_f32_16x16x32_bf16(a, b, acc, 0, 0, 0);
    }
    const float bv = bo2[ch];
#pragma unroll
    for (int r = 0; r < 4; ++r) {
      const int s = m * 16 + lg * 4 + r;
      g2[(size_t)(sb + s) * HDIM + ch] = (__bf16)fast_tanh(acc[r] + bv);
    }
  }
  __syncthreads();

  // L3d: buf2 -> xd (no tanh), 8 tiles (m2 x n4), one per wave
  {
    const int m = wave >> 2, n = wave & 3;
    const int ch = n * 16 + lr;
    f32x4 acc = {0.f, 0.f, 0.f, 0.f};
#pragma unroll
    for (int ks = 0; ks < 8; ++ks) {
      bf16x8 a = *(const bf16x8*)(buf2 + ((ks * 4 + lg) * 32 + m * 16 + lr) * 8);
      bf16x8 b = *(const bf16x8*)(Wdo + ch * HDIM + ks * 32 + lg * 8);
      acc = __builtin_amdgcn_mfma_f32_16x16x32_bf16(a, b, acc, 0, 0, 0);
    }
    const float bv = bdo[ch];
#pragma unroll
    for (int r = 0; r < 4; ++r) {
      const int s = m * 16 + lg * 4 + r;
      xd[(size_t)(sb + s) * NDIM + ch] = acc[r] + bv;
    }
  }
}

// ---------------- K2: Woo GEMM -> LDS z (pair-interleaved padded tri) + apply ----
// LDS: zt 16 pairs x ZROW x 2 bf16 = 135168 B; ys2 32x64 f32 pair-interleaved = 8192 B;
//      offtab 2016 u16 = 4032 B (pad 4096).  Total 147456 B.
#define ZT_BYTES   (16 * ZROW * 2 * 2)
#define YS_OFF     ZT_BYTES
#define TAB_OFF    (ZT_BYTES + 8192)
#define K2_SMEM    (ZT_BYTES + 8192 + 4096)

__global__ __launch_bounds__(1024, 4) void offdiag_apply_kernel(
    const __bf16* __restrict__ g2, const __bf16* __restrict__ Woo,
    const float* __restrict__ boo, const float* __restrict__ xd,
    const float* __restrict__ x0, float* __restrict__ out) {
  extern __shared__ char smem[];
  __bf16* ztb = (__bf16*)smem;                                 // units: pair*4224 + off*2 + (s&1)
  float* ys2 = (float*)(smem + YS_OFF);                        // [pair][64][2]
  unsigned short* offtab = (unsigned short*)(smem + TAB_OFF);  // [2016]

  const int tid = threadIdx.x;
  const int wave = tid >> 6, lane = tid & 63;
  const int lr = lane & 15, lg = lane >> 4;
  const int sb = blockIdx.x * 32;

  // zero zt (pads must be 0); build off-table
  {
    float4 z4 = {0.f, 0.f, 0.f, 0.f};
    float4* p = (float4*)smem;
    for (int i = tid; i < ZT_BYTES / 16; i += 1024) p[i] = z4;
    for (int q = tid; q < OFFD; q += 1024) {
      const float sq = sqrtf((float)(1 + 8 * q));
      const int i = (int)((1.f + sq) * 0.5f);
      const int tri = (i * (i - 1)) >> 1;
      const int r3 = i & 3;
      const int rs = tri + 6 * (i >> 2) + ((r3 == 2) ? 3 : (r3 == 3) ? 5 : 0);
      offtab[q] = (unsigned short)(rs + (q - tri));
    }
  }

  // A-fragments (32 samples of g2) held in registers for the whole GEMM
  bf16x8 afr[2][8];
#pragma unroll
  for (int m2 = 0; m2 < 2; ++m2)
#pragma unroll
    for (int ks = 0; ks < 8; ++ks)
      afr[m2][ks] =
          *(const bf16x8*)(g2 + (size_t)(sb + m2 * 16 + lr) * HDIM + ks * 32 + lg * 8);
  __syncthreads();

  // GEMM: z[32 x 2016] = G @ Woo^T + boo, scattered into padded-tri pair layout
  const int pb0 = lg * 2 * 4224;  // pair base units for sA = lg*4 + r
  for (int n = wave; n < OFFD / 16; n += 16) {
    const __bf16* wp = Woo + (size_t)(n * 16 + lr) * HDIM + lg * 8;
    bf16x8 bfr[8];
#pragma unroll
    for (int ks = 0; ks < 8; ++ks) bfr[ks] = *(const bf16x8*)(wp + ks * 32);
    f32x4 acc0 = {0.f, 0.f, 0.f, 0.f}, acc1 = {0.f, 0.f, 0.f, 0.f};
#pragma unroll
    for (int ks = 0; ks < 8; ++ks) {
      acc0 = __builtin_amdgcn_mfma_f32_16x16x32_bf16(afr[0][ks], bfr[ks], acc0, 0, 0, 0);
      acc1 = __builtin_amdgcn_mfma_f32_16x16x32_bf16(afr[1][ks], bfr[ks], acc1, 0, 0, 0);
    }
    const int col = n * 16 + lr;
    const float bv = boo[col];
    const int offv = (int)offtab[col];
#pragma unroll
    for (int r = 0; r < 4; ++r) {
      const int u = pb0 + (r >> 1) * 4224 + (r & 1) + offv * 2;
      ztb[u] = (__bf16)(acc0[r] + bv);                 // samples lg*4+r
      ztb[u + 8 * 4224] = (__bf16)(acc1[r] + bv);      // samples lg*4+r+16
    }
  }
  __syncthreads();

  // Apply: wave = sample pair (s0=2w, s1=2w+1); lane = vector index.
  const int s0 = wave * 2, s1 = s0 + 1;
  const __bf16* zpair = ztb + wave * 4224;
  const float x0vA = x0[(size_t)(sb + s0) * 64 + lane];
  const float x0vB = x0[(size_t)(sb + s1) * 64 + lane];
  const float xdA = xd[(size_t)(sb + s0) * 64 + lane];
  const float xdB = xd[(size_t)(sb + s1) * 64 + lane];

  // pass 1: y_j = xd_j x0_j + sum_{k>j} z[k][j] x0_k   (one b32 read = both samples)
  float yA = xdA * x0vA, yB = xdB * x0vB;
  int rs = 0;
  for (int k = 1; k < 64; ++k) {
    const unsigned w = *(const unsigned*)(zpair + (rs + lane) * 2);
    const float xkA = lane_bcast(x0vA, k);
    const float xkB = lane_bcast(x0vB, k);
    const bool mvalid = lane < k;
    yA += mvalid ? bf_lo(w) * xkA : 0.f;
    yB += mvalid ? bf_hi(w) * xkB : 0.f;
    rs += (k + 3) & ~3;
  }

  // publish y (pair-interleaved), same wave consumes
  float* yp = ys2 + wave * 128;
  *(float2*)(yp + lane * 2) = make_float2(yA, yB);

  // pass 2: D_i = xd_i y_i + sum_{j<i} z[i][j] y_j   (b128 = 4 j x 2 samples; zero pads)
  float DA = xdA * yA, DB = xdB * yB;
  float dA1 = 0.f, dB1 = 0.f;
  {
    const int r3 = lane & 3;
    const int rsi = ((lane * (lane - 1)) >> 1) + 6 * (lane >> 2) +
                    ((r3 == 2) ? 3 : (r3 == 3) ? 5 : 0);
    const int cmax = (lane + 3) >> 2;
    const __bf16* zrow = zpair + rsi * 2;
    for (int c = 0; c < cmax; ++c) {
      const uint4 w = *(const uint4*)(zrow + c * 8);
      const float4 u0 = *(const float4*)(yp + c * 8);      // yA[4c],yB[4c],yA[4c+1],yB[4c+1]
      const float4 u1 = *(const float4*)(yp + c * 8 + 4);  // next two j
      DA += bf_lo(w.x) * u0.x + bf_lo(w.z) * u1.x;
      dA1 += bf_lo(w.y) * u0.z + bf_lo(w.w) * u1.z;
      DB += bf_hi(w.x) * u0.y + bf_hi(w.z) * u1.y;
      dB1 += bf_hi(w.y) * u0.w + bf_hi(w.w) * u1.w;
    }
  }
  out[(size_t)(sb + s0) * 64 + lane] = DA + dA1;
  out[(size_t)(sb + s1) * 64 + lane] = DB + dB1;
}

// ---------------- launch ----------------
extern "C" void kernel_launch(void* const* d_in, const int* in_sizes, int n_in,
                              void* d_out, int out_size, void* d_ws, size_t ws_size,
                              hipStream_t stream) {
  const float* x   = (const float*)d_in[0];
  const float* Wd1 = (const float*)d_in[1];
  const float* bd1 = (const float*)d_in[2];
  const float* Wd2 = (const float*)d_in[3];
  const float* bd2 = (const float*)d_in[4];
  const float* Wdo = (const float*)d_in[5];
  const float* bdo = (const float*)d_in[6];
  const float* Wo1 = (const float*)d_in[7];
  const float* bo1 = (const float*)d_in[8];
  const float* Wo2 = (const float*)d_in[9];
  const float* bo2 = (const float*)d_in[10];
  const float* Woo = (const float*)d_in[11];
  const float* boo = (const float*)d_in[12];
  float* out = (float*)d_out;

  char* ws = (char*)d_ws;
  __bf16* W1b  = (__bf16*)(ws + 0);         //  65536 B (Wd1 rows 0-255, Wo1 rows 256-511)
  __bf16* Wd2b = (__bf16*)(ws + 65536);     // 131072 B
  __bf16* Wo2b = (__bf16*)(ws + 196608);    // 131072 B
  __bf16* Wdob = (__bf16*)(ws + 327680);    //  32768 B
  __bf16* Woob = (__bf16*)(ws + 360448);    // 1032192 B
  __bf16* g2   = (__bf16*)(ws + 1392640);   // B*256*2 = 16777216 B
  float*  xdp  = (float*)(ws + 18169856);   // B*64*4  =  8388608 B

  cast_all_kernel<<<512, 256, 0, stream>>>(
      Wd1, W1b, HDIM * NDIM,
      Wo1, W1b + HDIM * NDIM, HDIM * NDIM,
      Wd2, Wd2b, HDIM * HDIM,
      Wo2, Wo2b, HDIM * HDIM,
      Wdo, Wdob, NDIM * HDIM,
      Woo, Woob, OFFD * HDIM);

  trunk_kernel<<<B_TOT / 32, 512, 0, stream>>>(x, W1b, bd1, bo1, Wd2b, bd2, Wdob, bdo,
                                               Wo2b, bo2, g2, xdp);

  hipFuncSetAttribute((const void*)offdiag_apply_kernel,
                      hipFuncAttributeMaxDynamicSharedMemorySize, K2_SMEM);
  offdiag_apply_kernel<<<B_TOT / 32, 1024, K2_SMEM, stream>>>(g2, Woob, boo, xdp, x, out);
}

// Round 6
// 258.697 us; speedup vs baseline: 1.1974x; 1.1974x over previous
//
#include <hip/hip_runtime.h>
#include <math.h>

// Damping: B=32768, N=64, H=256, OFF=2016
//   diag: x -> tanh(Wd1) -> tanh(Wd2) -> Wdo   (64 per sample)
//   off : x -> tanh(Wo1) -> tanh(Wo2) -> Woo   (2016 per sample, strict lower tri)
//   out = L (L^T x0), L diag = xd, L[i][j](j<i) = z[i(i-1)/2+j]

#define B_TOT 32768
#define NDIM  64
#define HDIM  256
#define OFFD  2016

typedef __bf16 bf16x8 __attribute__((ext_vector_type(8)));
typedef float  f32x4  __attribute__((ext_vector_type(4)));

__device__ __forceinline__ float fast_tanh(float x) {
  float e = __expf(2.f * x);
  return 1.f - 2.f * __builtin_amdgcn_rcpf(e + 1.f);
}
__device__ __forceinline__ float lane_bcast(float v, int l) {
  return __uint_as_float(__builtin_amdgcn_readlane(__float_as_uint(v), l));
}
__device__ __forceinline__ float bf_lo(unsigned w) { return __uint_as_float(w << 16); }
__device__ __forceinline__ float bf_hi(unsigned w) { return __uint_as_float(w & 0xffff0000u); }

// ---------------- weight cast (f32 -> bf16), single launch ----------------
__device__ __forceinline__ void cast_range(const float* __restrict__ s,
                                           __bf16* __restrict__ d, int n) {
  int i = blockIdx.x * blockDim.x + threadIdx.x;
  const int stride = gridDim.x * blockDim.x;
  for (; i < n; i += stride) d[i] = (__bf16)s[i];
}
__global__ __launch_bounds__(256) void cast_all_kernel(
    const float* s0, __bf16* d0, int n0, const float* s1, __bf16* d1, int n1,
    const float* s2, __bf16* d2, int n2, const float* s3, __bf16* d3, int n3,
    const float* s4, __bf16* d4, int n4, const float* s5, __bf16* d5, int n5) {
  cast_range(s0, d0, n0); cast_range(s1, d1, n1); cast_range(s2, d2, n2);
  cast_range(s3, d3, n3); cast_range(s4, d4, n4); cast_range(s5, d5, n5);
}

__device__ __forceinline__ bf16x8 cvt8(const float* __restrict__ p) {
  const float4 u = *(const float4*)p;
  const float4 v = *(const float4*)(p + 4);
  bf16x8 r;
  r[0] = (__bf16)u.x; r[1] = (__bf16)u.y; r[2] = (__bf16)u.z; r[3] = (__bf16)u.w;
  r[4] = (__bf16)v.x; r[5] = (__bf16)v.y; r[6] = (__bf16)v.z; r[7] = (__bf16)v.w;
  return r;
}

#define MFMA(A, B, C) __builtin_amdgcn_mfma_f32_16x16x32_bf16((A), (B), (C), 0, 0, 0)

// 8 named B loads from global, stride 32 ch (64 B)
#define LDB8(P)                                   \
  const bf16x8 b0 = *(const bf16x8*)(P);          \
  const bf16x8 b1 = *(const bf16x8*)((P) + 32);   \
  const bf16x8 b2 = *(const bf16x8*)((P) + 64);   \
  const bf16x8 b3 = *(const bf16x8*)((P) + 96);   \
  const bf16x8 b4 = *(const bf16x8*)((P) + 128);  \
  const bf16x8 b5 = *(const bf16x8*)((P) + 160);  \
  const bf16x8 b6 = *(const bf16x8*)((P) + 192);  \
  const bf16x8 b7 = *(const bf16x8*)((P) + 224);

// 8 named A reads from chunked LDS, stride 1024 units per ks
#define LDA8(P)                                     \
  const bf16x8 a0 = *(const bf16x8*)(P);            \
  const bf16x8 a1 = *(const bf16x8*)((P) + 1024);   \
  const bf16x8 a2 = *(const bf16x8*)((P) + 2048);   \
  const bf16x8 a3 = *(const bf16x8*)((P) + 3072);   \
  const bf16x8 a4 = *(const bf16x8*)((P) + 4096);   \
  const bf16x8 a5 = *(const bf16x8*)((P) + 5120);   \
  const bf16x8 a6 = *(const bf16x8*)((P) + 6144);   \
  const bf16x8 a7 = *(const bf16x8*)((P) + 7168);

#define MFMA8(ACC)            \
  ACC = MFMA(a0, b0, ACC);    \
  ACC = MFMA(a1, b1, ACC);    \
  ACC = MFMA(a2, b2, ACC);    \
  ACC = MFMA(a3, b3, ACC);    \
  ACC = MFMA(a4, b4, ACC);    \
  ACC = MFMA(a5, b5, ACC);    \
  ACC = MFMA(a6, b6, ACC);    \
  ACC = MFMA(a7, b7, ACC);

// ---------------- K1: both MLP trunks, 32 samples / WG, 8 waves ----------------
// chunked LDS: unit = (ch>>3)*256 + s*8 + (ch&7)   (chunk stride 256 units = 512 B)
__global__ __launch_bounds__(512, 4) void trunk_kernel(
    const float* __restrict__ x, const __bf16* __restrict__ W1,
    const float* __restrict__ bd1, const float* __restrict__ bo1,
    const __bf16* __restrict__ Wd2, const float* __restrict__ bd2,
    const __bf16* __restrict__ Wdo, const float* __restrict__ bdo,
    const __bf16* __restrict__ Wo2, const float* __restrict__ bo2,
    __bf16* __restrict__ g2, float* __restrict__ xd) {
  __shared__ __bf16 ch512[64 * 256];  // 32 KB: h1 chunks 0..31, g1 chunks 32..63
  __shared__ __bf16 buf2[32 * 256];   // 16 KB: h2
  const int tid = threadIdx.x;
  const int wave = tid >> 6, lane = tid & 63;
  const int lr = lane & 15, lg = lane >> 4;
  const int sb = blockIdx.x * 32;

  // x A-fragments, named (no arrays -> cannot demote to scratch)
  const float* xb = x + (size_t)(sb + lr) * NDIM + lg * 8;
  const bf16x8 ax00 = cvt8(xb);
  const bf16x8 ax01 = cvt8(xb + 32);
  const bf16x8 ax10 = cvt8(xb + 16 * NDIM);
  const bf16x8 ax11 = cvt8(xb + 16 * NDIM + 32);

  // ---- L1 merged diag+off: 64 tiles (m2 x n32), K=64 ----
#pragma unroll
  for (int u = 0; u < 8; ++u) {
    const int n = wave + 8 * (u & 3);
    const int mrow = (u < 4) ? 0 : 16;
    const int ch = n * 16 + lr;
    const __bf16* wp = W1 + ch * NDIM + lg * 8;
    const bf16x8 wb0 = *(const bf16x8*)(wp);
    const bf16x8 wb1 = *(const bf16x8*)(wp + 32);
    __builtin_amdgcn_sched_barrier(0x120);
    f32x4 acc = {0.f, 0.f, 0.f, 0.f};
    acc = MFMA((u < 4) ? ax00 : ax10, wb0, acc);
    acc = MFMA((u < 4) ? ax01 : ax11, wb1, acc);
    const float bv = (ch < 256) ? bd1[ch] : bo1[ch - 256];
#pragma unroll
    for (int r = 0; r < 4; ++r) {
      const int s = mrow + lg * 4 + r;
      ch512[(ch >> 3) * 256 + s * 8 + (ch & 7)] = (__bf16)fast_tanh(acc[r] + bv);
    }
  }
  __syncthreads();

  // ---- L2d: chunks 0..31 -> buf2 (tanh), K=256 ----
#pragma unroll
  for (int u = 0; u < 4; ++u) {
    const int n = wave + 8 * (u & 1);
    const int mrow = (u < 2) ? 0 : 16;
    const int ch = n * 16 + lr;
    LDB8(Wd2 + ch * HDIM + lg * 8)
    LDA8(ch512 + (mrow + lr) * 8 + lg * 256)
    __builtin_amdgcn_sched_barrier(0x120);
    f32x4 acc = {0.f, 0.f, 0.f, 0.f};
    MFMA8(acc)
    const float bv = bd2[ch];
#pragma unroll
    for (int r = 0; r < 4; ++r) {
      const int s = mrow + lg * 4 + r;
      buf2[(ch >> 3) * 256 + s * 8 + (ch & 7)] = (__bf16)fast_tanh(acc[r] + bv);
    }
  }
  // ---- L2o: chunks 32..63 -> g2 global (tanh), K=256 ----
#pragma unroll
  for (int u = 0; u < 4; ++u) {
    const int n = wave + 8 * (u & 1);
    const int mrow = (u < 2) ? 0 : 16;
    const int ch = n * 16 + lr;
    LDB8(Wo2 + ch * HDIM + lg * 8)
    LDA8(ch512 + 8192 + (mrow + lr) * 8 + lg * 256)
    __builtin_amdgcn_sched_barrier(0x120);
    f32x4 acc = {0.f, 0.f, 0.f, 0.f};
    MFMA8(acc)
    const float bv = bo2[ch];
#pragma unroll
    for (int r = 0; r < 4; ++r) {
      const int s = mrow + lg * 4 + r;
      g2[(size_t)(sb + s) * HDIM + ch] = (__bf16)fast_tanh(acc[r] + bv);
    }
  }
  __syncthreads();

  // ---- L3d: buf2 -> xd (no tanh), 8 tiles, one per wave ----
  {
    const int mrow = (wave >> 2) * 16;
    const int n = wave & 3;
    const int ch = n * 16 + lr;
    LDB8(Wdo + ch * HDIM + lg * 8)
    LDA8(buf2 + (mrow + lr) * 8 + lg * 256)
    __builtin_amdgcn_sched_barrier(0x120);
    f32x4 acc = {0.f, 0.f, 0.f, 0.f};
    MFMA8(acc)
    const float bv = bdo[ch];
#pragma unroll
    for (int r = 0; r < 4; ++r) {
      const int s = mrow + lg * 4 + r;
      xd[(size_t)(sb + s) * NDIM + ch] = acc[r] + bv;
    }
  }
}

// ---------------- K2: Woo GEMM -> LDS z (pair-interleaved padded tri) + apply ----
// LDS: zt 16 pairs x 2112 offs x 2 bf16 = 135168 B; ys2 = 8192 B; atile = 16384 B.
#define ZT_BYTES 135168
#define K2_SMEM  (ZT_BYTES + 8192 + 16384)

__global__ __launch_bounds__(1024, 4) void offdiag_apply_kernel(
    const __bf16* __restrict__ g2, const __bf16* __restrict__ Woo,
    const float* __restrict__ boo, const float* __restrict__ xd,
    const float* __restrict__ x0, float* __restrict__ out) {
  extern __shared__ char smem[];
  __bf16* ztb = (__bf16*)smem;                    // unit: pair*4224 + off*2 + (s&1)
  float* ys2 = (float*)(smem + ZT_BYTES);         // [pair][64][2]
  __bf16* at = (__bf16*)(smem + ZT_BYTES + 8192); // chunked [32ch-grp][32 s][8]

  const int tid = threadIdx.x;
  const int wave = tid >> 6, lane = tid & 63;
  const int lr = lane & 15, lg = lane >> 4;
  const int sb = blockIdx.x * 32;

  // zero zt (pads must be 0)
  {
    float4 z4 = {0.f, 0.f, 0.f, 0.f};
    float4* p = (float4*)smem;
#pragma unroll
    for (int i = 0; i < 9; ++i) {
      const int idx = tid + i * 1024;
      if (idx < ZT_BYTES / 16) p[idx] = z4;
    }
  }
  // stage g2 tile into chunked atile: 1024 threads x 16 B
  {
    const int s = tid >> 5, cg = tid & 31;
    *(bf16x8*)(at + cg * 256 + s * 8) =
        *(const bf16x8*)(g2 + (size_t)(sb + s) * HDIM + cg * 8);
  }
  __syncthreads();

  // GEMM: z[32 x 2016] = G @ Woo^T + boo, scattered into padded-tri pair layout
  const int pb0 = lg * 8448;  // pair base units for sA = lg*4 + r
  for (int it = 0; it < 8; ++it) {
    const int n = wave + 16 * it;
    if (n >= OFFD / 16) break;
    const int col = n * 16 + lr;
    f32x4 acc0 = {0.f, 0.f, 0.f, 0.f}, acc1 = {0.f, 0.f, 0.f, 0.f};
    {
      LDB8(Woo + (size_t)col * HDIM + lg * 8)
      {
        LDA8(at + lr * 8 + lg * 256)          // samples lr (m=0)
        __builtin_amdgcn_sched_barrier(0x120);
        MFMA8(acc0)
      }
      {
        LDA8(at + (16 + lr) * 8 + lg * 256)   // samples 16+lr (m=1)
        __builtin_amdgcn_sched_barrier(0x120);
        MFMA8(acc1)
      }
    }
    // scatter into padded triangle (row i padded to x4, zero-filled)
    const float sq = sqrtf((float)(1 + 8 * col));
    const int i = (int)((1.f + sq) * 0.5f);
    const int tri = (i * (i - 1)) >> 1;
    const int r3 = i & 3;
    const int offv = tri + 6 * (i >> 2) + ((r3 == 2) ? 3 : (r3 == 3) ? 5 : 0) + (col - tri);
    const float bv = boo[col];
#pragma unroll
    for (int r = 0; r < 4; ++r) {
      const int u = pb0 + (r >> 1) * 4224 + (r & 1) + offv * 2;
      ztb[u] = (__bf16)(acc0[r] + bv);             // samples lg*4+r
      ztb[u + 33792] = (__bf16)(acc1[r] + bv);     // samples lg*4+r+16
    }
  }
  __syncthreads();

  // Apply: wave = sample pair (s0=2w, s1=2w+1); lane = vector index.
  const int s0 = wave * 2, s1 = s0 + 1;
  const __bf16* zpair = ztb + wave * 4224;
  const float x0vA = x0[(size_t)(sb + s0) * 64 + lane];
  const float x0vB = x0[(size_t)(sb + s1) * 64 + lane];
  const float xdA = xd[(size_t)(sb + s0) * 64 + lane];
  const float xdB = xd[(size_t)(sb + s1) * 64 + lane];

  // pass 1: y_j = xd_j x0_j + sum_{k>j} z[k][j] x0_k  (one b32 read = both samples)
  float yA = xdA * x0vA, yB = xdB * x0vB;
  int rs = 0;
  for (int k = 1; k < 64; ++k) {
    const unsigned w = *(const unsigned*)(zpair + (rs + lane) * 2);
    const float xkA = lane_bcast(x0vA, k);
    const float xkB = lane_bcast(x0vB, k);
    const bool mvalid = lane < k;
    yA += mvalid ? bf_lo(w) * xkA : 0.f;
    yB += mvalid ? bf_hi(w) * xkB : 0.f;
    rs += (k + 3) & ~3;
  }

  // publish y (pair-interleaved), same wave consumes
  float* yp = ys2 + wave * 128;
  *(float2*)(yp + lane * 2) = make_float2(yA, yB);

  // pass 2: D_i = xd_i y_i + sum_{j<i} z[i][j] y_j  (b128 = 4 j x 2 samples; zero pads)
  float DA = xdA * yA, DB = xdB * yB;
  float dA1 = 0.f, dB1 = 0.f;
  {
    const int r3 = lane & 3;
    const int rsi = ((lane * (lane - 1)) >> 1) + 6 * (lane >> 2) +
                    ((r3 == 2) ? 3 : (r3 == 3) ? 5 : 0);
    const int cmax = (lane + 3) >> 2;
    const __bf16* zrow = zpair + rsi * 2;
    for (int c = 0; c < cmax; ++c) {
      const uint4 w = *(const uint4*)(zrow + c * 8);
      const float4 u0 = *(const float4*)(yp + c * 8);
      const float4 u1 = *(const float4*)(yp + c * 8 + 4);
      DA += bf_lo(w.x) * u0.x + bf_lo(w.z) * u1.x;
      dA1 += bf_lo(w.y) * u0.z + bf_lo(w.w) * u1.z;
      DB += bf_hi(w.x) * u0.y + bf_hi(w.z) * u1.y;
      dB1 += bf_hi(w.y) * u0.w + bf_hi(w.w) * u1.w;
    }
  }
  out[(size_t)(sb + s0) * 64 + lane] = DA + dA1;
  out[(size_t)(sb + s1) * 64 + lane] = DB + dB1;
}

// ---------------- launch ----------------
extern "C" void kernel_launch(void* const* d_in, const int* in_sizes, int n_in,
                              void* d_out, int out_size, void* d_ws, size_t ws_size,
                              hipStream_t stream) {
  const float* x   = (const float*)d_in[0];
  const float* Wd1 = (const float*)d_in[1];
  const float* bd1 = (const float*)d_in[2];
  const float* Wd2 = (const float*)d_in[3];
  const float* bd2 = (const float*)d_in[4];
  const float* Wdo = (const float*)d_in[5];
  const float* bdo = (const float*)d_in[6];
  const float* Wo1 = (const float*)d_in[7];
  const float* bo1 = (const float*)d_in[8];
  const float* Wo2 = (const float*)d_in[9];
  const float* bo2 = (const float*)d_in[10];
  const float* Woo = (const float*)d_in[11];
  const float* boo = (const float*)d_in[12];
  float* out = (float*)d_out;

  char* ws = (char*)d_ws;
  __bf16* W1b  = (__bf16*)(ws + 0);         //  65536 B (Wd1 rows 0-255, Wo1 rows 256-511)
  __bf16* Wd2b = (__bf16*)(ws + 65536);     // 131072 B
  __bf16* Wo2b = (__bf16*)(ws + 196608);    // 131072 B
  __bf16* Wdob = (__bf16*)(ws + 327680);    //  32768 B
  __bf16* Woob = (__bf16*)(ws + 360448);    // 1032192 B
  __bf16* g2   = (__bf16*)(ws + 1392640);   // B*256*2 = 16777216 B
  float*  xdp  = (float*)(ws + 18169856);   // B*64*4  =  8388608 B

  cast_all_kernel<<<512, 256, 0, stream>>>(
      Wd1, W1b, HDIM * NDIM,
      Wo1, W1b + HDIM * NDIM, HDIM * NDIM,
      Wd2, Wd2b, HDIM * HDIM,
      Wo2, Wo2b, HDIM * HDIM,
      Wdo, Wdob, NDIM * HDIM,
      Woo, Woob, OFFD * HDIM);

  trunk_kernel<<<B_TOT / 32, 512, 0, stream>>>(x, W1b, bd1, bo1, Wd2b, bd2, Wdob, bdo,
                                               Wo2b, bo2, g2, xdp);

  hipFuncSetAttribute((const void*)offdiag_apply_kernel,
                      hipFuncAttributeMaxDynamicSharedMemorySize, K2_SMEM);
  offdiag_apply_kernel<<<B_TOT / 32, 1024, K2_SMEM, stream>>>(g2, Woob, boo, xdp, x, out);
}

// Round 7
// 219.688 us; speedup vs baseline: 1.4101x; 1.1776x over previous
//
#include <hip/hip_runtime.h>
#include <math.h>

// Damping: B=32768, N=64, H=256, OFF=2016
//   diag: x -> tanh(Wd1) -> tanh(Wd2) -> Wdo   (64 per sample)
//   off : x -> tanh(Wo1) -> tanh(Wo2) -> Woo   (2016 per sample, strict lower tri)
//   out = L (L^T x0), L diag = xd, L[i][j](j<i) = z[i(i-1)/2+j]

#define B_TOT 32768
#define NDIM  64
#define HDIM  256
#define OFFD  2016

typedef __bf16 bf16x8 __attribute__((ext_vector_type(8)));
typedef float  f32x4  __attribute__((ext_vector_type(4)));

__device__ __forceinline__ float fast_tanh(float x) {
  float e = __expf(2.f * x);
  return 1.f - 2.f * __builtin_amdgcn_rcpf(e + 1.f);
}
__device__ __forceinline__ float lane_bcast(float v, int l) {
  return __uint_as_float(__builtin_amdgcn_readlane(__float_as_uint(v), l));
}
__device__ __forceinline__ float bf_lo(unsigned w) { return __uint_as_float(w << 16); }
__device__ __forceinline__ float bf_hi(unsigned w) { return __uint_as_float(w & 0xffff0000u); }

// ---------------- weight cast (f32 -> bf16), single launch ----------------
__device__ __forceinline__ void cast_range(const float* __restrict__ s,
                                           __bf16* __restrict__ d, int n) {
  int i = blockIdx.x * blockDim.x + threadIdx.x;
  const int stride = gridDim.x * blockDim.x;
  for (; i < n; i += stride) d[i] = (__bf16)s[i];
}
__global__ __launch_bounds__(256) void cast_all_kernel(
    const float* s0, __bf16* d0, int n0, const float* s1, __bf16* d1, int n1,
    const float* s2, __bf16* d2, int n2, const float* s3, __bf16* d3, int n3,
    const float* s4, __bf16* d4, int n4, const float* s5, __bf16* d5, int n5) {
  cast_range(s0, d0, n0); cast_range(s1, d1, n1); cast_range(s2, d2, n2);
  cast_range(s3, d3, n3); cast_range(s4, d4, n4); cast_range(s5, d5, n5);
}

__device__ __forceinline__ bf16x8 cvt8(const float* __restrict__ p) {
  const float4 u = *(const float4*)p;
  const float4 v = *(const float4*)(p + 4);
  bf16x8 r;
  r[0] = (__bf16)u.x; r[1] = (__bf16)u.y; r[2] = (__bf16)u.z; r[3] = (__bf16)u.w;
  r[4] = (__bf16)v.x; r[5] = (__bf16)v.y; r[6] = (__bf16)v.z; r[7] = (__bf16)v.w;
  return r;
}

#define MFMA(A, B, C) __builtin_amdgcn_mfma_f32_16x16x32_bf16((A), (B), (C), 0, 0, 0)
#define SB0() __builtin_amdgcn_sched_barrier(0)

// 8 named B loads (V##0..V##7) from pointer P, stride 32 ch (64 B)
#define LDB8V(V, P)                                   \
  const bf16x8 V##0 = *(const bf16x8*)(P);            \
  const bf16x8 V##1 = *(const bf16x8*)((P) + 32);     \
  const bf16x8 V##2 = *(const bf16x8*)((P) + 64);     \
  const bf16x8 V##3 = *(const bf16x8*)((P) + 96);     \
  const bf16x8 V##4 = *(const bf16x8*)((P) + 128);    \
  const bf16x8 V##5 = *(const bf16x8*)((P) + 160);    \
  const bf16x8 V##6 = *(const bf16x8*)((P) + 192);    \
  const bf16x8 V##7 = *(const bf16x8*)((P) + 224);

#define DEFB8(V) bf16x8 V##0, V##1, V##2, V##3, V##4, V##5, V##6, V##7;
#define LDB8TO(V, P)                            \
  V##0 = *(const bf16x8*)(P);                   \
  V##1 = *(const bf16x8*)((P) + 32);            \
  V##2 = *(const bf16x8*)((P) + 64);            \
  V##3 = *(const bf16x8*)((P) + 96);            \
  V##4 = *(const bf16x8*)((P) + 128);           \
  V##5 = *(const bf16x8*)((P) + 160);           \
  V##6 = *(const bf16x8*)((P) + 192);           \
  V##7 = *(const bf16x8*)((P) + 224);
#define CPB8(D, S)                                            \
  D##0 = S##0; D##1 = S##1; D##2 = S##2; D##3 = S##3;         \
  D##4 = S##4; D##5 = S##5; D##6 = S##6; D##7 = S##7;

// 8 named A reads (a0..a7) from chunked LDS, stride 1024 units per ks
#define LDA8(P)                                     \
  const bf16x8 a0 = *(const bf16x8*)(P);            \
  const bf16x8 a1 = *(const bf16x8*)((P) + 1024);   \
  const bf16x8 a2 = *(const bf16x8*)((P) + 2048);   \
  const bf16x8 a3 = *(const bf16x8*)((P) + 3072);   \
  const bf16x8 a4 = *(const bf16x8*)((P) + 4096);   \
  const bf16x8 a5 = *(const bf16x8*)((P) + 5120);   \
  const bf16x8 a6 = *(const bf16x8*)((P) + 6144);   \
  const bf16x8 a7 = *(const bf16x8*)((P) + 7168);

#define MFMA8V(ACC, B)              \
  ACC = MFMA(a0, B##0, ACC);        \
  ACC = MFMA(a1, B##1, ACC);        \
  ACC = MFMA(a2, B##2, ACC);        \
  ACC = MFMA(a3, B##3, ACC);        \
  ACC = MFMA(a4, B##4, ACC);        \
  ACC = MFMA(a5, B##5, ACC);        \
  ACC = MFMA(a6, B##6, ACC);        \
  ACC = MFMA(a7, B##7, ACC);

// ---------------- K1: both MLP trunks, 32 samples / WG, 8 waves ----------------
// chunked LDS: unit = (ch>>3)*256 + s*8 + (ch&7)   (chunk stride 256 units)
__global__ __launch_bounds__(512, 4) void trunk_kernel(
    const float* __restrict__ x, const __bf16* __restrict__ W1,
    const float* __restrict__ bd1, const float* __restrict__ bo1,
    const __bf16* __restrict__ Wd2, const float* __restrict__ bd2,
    const __bf16* __restrict__ Wdo, const float* __restrict__ bdo,
    const __bf16* __restrict__ Wo2, const float* __restrict__ bo2,
    __bf16* __restrict__ g2, float* __restrict__ xd) {
  __shared__ __bf16 ch512[64 * 256];  // 32 KB: h1 chunks 0..31, g1 chunks 32..63
  __shared__ __bf16 buf2[32 * 256];   // 16 KB: h2
  const int tid = threadIdx.x;
  const int wave = tid >> 6, lane = tid & 63;
  const int lr = lane & 15, lg = lane >> 4;
  const int sb = blockIdx.x * 32;

  // x A-fragments, named
  const float* xb = x + (size_t)(sb + lr) * NDIM + lg * 8;
  const bf16x8 ax00 = cvt8(xb);
  const bf16x8 ax01 = cvt8(xb + 32);
  const bf16x8 ax10 = cvt8(xb + 16 * NDIM);
  const bf16x8 ax11 = cvt8(xb + 16 * NDIM + 32);

  // ---- L1 merged diag+off: B-tiles n = wave, wave+8, wave+16, wave+24 (hoisted) ----
  {
    const __bf16* w1p = W1 + (wave * 16 + lr) * NDIM + lg * 8;
    const bf16x8 p00 = *(const bf16x8*)(w1p);
    const bf16x8 p01 = *(const bf16x8*)(w1p + 32);
    const bf16x8 p10 = *(const bf16x8*)(w1p + 128 * NDIM);
    const bf16x8 p11 = *(const bf16x8*)(w1p + 128 * NDIM + 32);
    const bf16x8 p20 = *(const bf16x8*)(w1p + 256 * NDIM);
    const bf16x8 p21 = *(const bf16x8*)(w1p + 256 * NDIM + 32);
    const bf16x8 p30 = *(const bf16x8*)(w1p + 384 * NDIM);
    const bf16x8 p31 = *(const bf16x8*)(w1p + 384 * NDIM + 32);
    SB0();
#define L1TILE(B0, B1, A0, A1, NB, MROW)                                         \
    {                                                                            \
      f32x4 acc = {0.f, 0.f, 0.f, 0.f};                                          \
      acc = MFMA(A0, B0, acc);                                                   \
      acc = MFMA(A1, B1, acc);                                                   \
      const int ch = (NB) * 16 + lr;                                             \
      const float bv = (ch < 256) ? bd1[ch] : bo1[ch - 256];                     \
      _Pragma("unroll")                                                          \
      for (int r = 0; r < 4; ++r) {                                              \
        const int s = (MROW) + lg * 4 + r;                                       \
        ch512[(ch >> 3) * 256 + s * 8 + (ch & 7)] = (__bf16)fast_tanh(acc[r] + bv); \
      }                                                                          \
    }
    L1TILE(p00, p01, ax00, ax01, wave, 0)
    L1TILE(p10, p11, ax00, ax01, wave + 8, 0)
    L1TILE(p20, p21, ax00, ax01, wave + 16, 0)
    L1TILE(p30, p31, ax00, ax01, wave + 24, 0)
    L1TILE(p00, p01, ax10, ax11, wave, 16)
    L1TILE(p10, p11, ax10, ax11, wave + 8, 16)
    L1TILE(p20, p21, ax10, ax11, wave + 16, 16)
    L1TILE(p30, p31, ax10, ax11, wave + 24, 16)
  }
  __syncthreads();

  // ---- L2d: chunks 0..31 -> buf2 (tanh); B-tiles n = wave, wave+8 (hoisted) ----
  {
    LDB8V(p, Wd2 + (wave * 16 + lr) * HDIM + lg * 8)
    LDB8V(q, Wd2 + ((wave + 8) * 16 + lr) * HDIM + lg * 8)
    SB0();
#define L2STORE_BUF(ACC, NB, MROW)                                               \
    {                                                                            \
      const int ch = (NB) * 16 + lr;                                             \
      const float bv = bd2[ch];                                                  \
      _Pragma("unroll")                                                          \
      for (int r = 0; r < 4; ++r) {                                              \
        const int s = (MROW) + lg * 4 + r;                                       \
        buf2[(ch >> 3) * 256 + s * 8 + (ch & 7)] = (__bf16)fast_tanh(ACC[r] + bv); \
      }                                                                          \
    }
    {
      LDA8(ch512 + lr * 8 + lg * 256)
      f32x4 accp = {0.f, 0.f, 0.f, 0.f}, accq = {0.f, 0.f, 0.f, 0.f};
      MFMA8V(accp, p)
      MFMA8V(accq, q)
      L2STORE_BUF(accp, wave, 0)
      L2STORE_BUF(accq, wave + 8, 0)
    }
    {
      LDA8(ch512 + (16 + lr) * 8 + lg * 256)
      f32x4 accp = {0.f, 0.f, 0.f, 0.f}, accq = {0.f, 0.f, 0.f, 0.f};
      MFMA8V(accp, p)
      MFMA8V(accq, q)
      L2STORE_BUF(accp, wave, 16)
      L2STORE_BUF(accq, wave + 8, 16)
    }
  }
  // ---- L2o: chunks 32..63 -> g2 global (tanh); B-tiles n = wave, wave+8 ----
  {
    LDB8V(p, Wo2 + (wave * 16 + lr) * HDIM + lg * 8)
    LDB8V(q, Wo2 + ((wave + 8) * 16 + lr) * HDIM + lg * 8)
    SB0();
#define L2STORE_G2(ACC, NB, MROW)                                                \
    {                                                                            \
      const int ch = (NB) * 16 + lr;                                             \
      const float bv = bo2[ch];                                                  \
      _Pragma("unroll")                                                          \
      for (int r = 0; r < 4; ++r) {                                              \
        const int s = (MROW) + lg * 4 + r;                                       \
        g2[(size_t)(sb + s) * HDIM + ch] = (__bf16)fast_tanh(ACC[r] + bv);       \
      }                                                                          \
    }
    {
      LDA8(ch512 + 8192 + lr * 8 + lg * 256)
      f32x4 accp = {0.f, 0.f, 0.f, 0.f}, accq = {0.f, 0.f, 0.f, 0.f};
      MFMA8V(accp, p)
      MFMA8V(accq, q)
      L2STORE_G2(accp, wave, 0)
      L2STORE_G2(accq, wave + 8, 0)
    }
    {
      LDA8(ch512 + 8192 + (16 + lr) * 8 + lg * 256)
      f32x4 accp = {0.f, 0.f, 0.f, 0.f}, accq = {0.f, 0.f, 0.f, 0.f};
      MFMA8V(accp, p)
      MFMA8V(accq, q)
      L2STORE_G2(accp, wave, 16)
      L2STORE_G2(accq, wave + 8, 16)
    }
  }
  __syncthreads();

  // ---- L3d: buf2 -> xd (no tanh), 8 tiles, one per wave ----
  {
    const int mrow = (wave >> 2) * 16;
    const int ch = (wave & 3) * 16 + lr;
    LDB8V(p, Wdo + ch * HDIM + lg * 8)
    SB0();
    LDA8(buf2 + (mrow + lr) * 8 + lg * 256)
    f32x4 acc = {0.f, 0.f, 0.f, 0.f};
    MFMA8V(acc, p)
    const float bv = bdo[ch];
#pragma unroll
    for (int r = 0; r < 4; ++r) {
      const int s = mrow + lg * 4 + r;
      xd[(size_t)(sb + s) * NDIM + ch] = acc[r] + bv;
    }
  }
}

// ---------------- K2: Woo GEMM -> LDS z (pair-interleaved padded tri) + apply ----
// LDS: zt 16 pairs x 2112 offs x 2 bf16 = 135168 B; ys2 = 8192 B; atile = 16384 B.
#define ZT_BYTES 135168
#define K2_SMEM  (ZT_BYTES + 8192 + 16384)

__global__ __launch_bounds__(1024, 4) void offdiag_apply_kernel(
    const __bf16* __restrict__ g2, const __bf16* __restrict__ Woo,
    const float* __restrict__ boo, const float* __restrict__ xd,
    const float* __restrict__ x0, float* __restrict__ out) {
  extern __shared__ char smem[];
  __bf16* ztb = (__bf16*)smem;                    // unit: pair*4224 + off*2 + (s&1)
  float* ys2 = (float*)(smem + ZT_BYTES);         // [pair][64][2]
  __bf16* at = (__bf16*)(smem + ZT_BYTES + 8192); // chunked [32ch-grp][32 s][8]

  const int tid = threadIdx.x;
  const int wave = tid >> 6, lane = tid & 63;
  const int lr = lane & 15, lg = lane >> 4;
  const int sb = blockIdx.x * 32;

  // zero zt (pads must be 0)
  {
    float4 z4 = {0.f, 0.f, 0.f, 0.f};
    float4* p = (float4*)smem;
#pragma unroll
    for (int i = 0; i < 9; ++i) {
      const int idx = tid + i * 1024;
      if (idx < ZT_BYTES / 16) p[idx] = z4;
    }
  }
  // stage g2 tile into chunked atile: 1024 threads x 16 B
  {
    const int s = tid >> 5, cg = tid & 31;
    *(bf16x8*)(at + cg * 256 + s * 8) =
        *(const bf16x8*)(g2 + (size_t)(sb + s) * HDIM + cg * 8);
  }
  __syncthreads();

  // GEMM: z[32 x 2016] = G @ Woo^T + boo, 2-deep double-buffered B registers.
  const int pb0 = lg * 8448;  // pair base units for sA = lg*4 + r
  DEFB8(bc)
  {
    const __bf16* wp = Woo + (size_t)(wave * 16 + lr) * HDIM + lg * 8;
    LDB8TO(bc, wp)
  }
#pragma unroll
  for (int it = 0; it < 8; ++it) {
    const int ncur = wave + 16 * it;
    int nnxt = wave + 16 * (it + 1);
    if (nnxt > 125) nnxt = 125;
    const __bf16* wpn = Woo + (size_t)(nnxt * 16 + lr) * HDIM + lg * 8;
    LDB8V(bn, wpn)
    SB0();  // pin prefetch issue above the compute; MFMAs wait only on bc (vmcnt(8))
    f32x4 acc0 = {0.f, 0.f, 0.f, 0.f}, acc1 = {0.f, 0.f, 0.f, 0.f};
    {
      LDA8(at + lr * 8 + lg * 256)        // samples lr (m=0)
      MFMA8V(acc0, bc)
    }
    {
      LDA8(at + (16 + lr) * 8 + lg * 256) // samples 16+lr (m=1)
      MFMA8V(acc1, bc)
    }
    if (ncur < 126) {
      const int col = ncur * 16 + lr;
      // scatter into padded triangle (row i padded to x4, zero-filled)
      const float sq = sqrtf((float)(1 + 8 * col));
      const int i = (int)((1.f + sq) * 0.5f);
      const int tri = (i * (i - 1)) >> 1;
      const int r3 = i & 3;
      const int offv =
          tri + 6 * (i >> 2) + ((r3 == 2) ? 3 : (r3 == 3) ? 5 : 0) + (col - tri);
      const float bv = boo[col];
#pragma unroll
      for (int r = 0; r < 4; ++r) {
        const int u = pb0 + (r >> 1) * 4224 + (r & 1) + offv * 2;
        ztb[u] = (__bf16)(acc0[r] + bv);             // samples lg*4+r
        ztb[u + 33792] = (__bf16)(acc1[r] + bv);     // samples lg*4+r+16
      }
    }
    CPB8(bc, bn)
  }
  __syncthreads();

  // Apply: wave = sample pair (s0=2w, s1=2w+1); lane = vector index.
  const int s0 = wave * 2, s1 = s0 + 1;
  const __bf16* zpair = ztb + wave * 4224;
  const float x0vA = x0[(size_t)(sb + s0) * 64 + lane];
  const float x0vB = x0[(size_t)(sb + s1) * 64 + lane];
  const float xdA = xd[(size_t)(sb + s0) * 64 + lane];
  const float xdB = xd[(size_t)(sb + s1) * 64 + lane];

  // pass 1: y_j = xd_j x0_j + sum_{k>j} z[k][j] x0_k  (one b32 read = both samples)
  float yA = xdA * x0vA, yB = xdB * x0vB;
  int rs = 0;
#pragma unroll
  for (int k = 1; k < 64; ++k) {
    const unsigned w = *(const unsigned*)(zpair + (rs + lane) * 2);
    const float xkA = lane_bcast(x0vA, k);
    const float xkB = lane_bcast(x0vB, k);
    const bool mvalid = lane < k;
    yA += mvalid ? bf_lo(w) * xkA : 0.f;
    yB += mvalid ? bf_hi(w) * xkB : 0.f;
    rs += (k + 3) & ~3;
  }

  // publish y (pair-interleaved), same wave consumes
  float* yp = ys2 + wave * 128;
  *(float2*)(yp + lane * 2) = make_float2(yA, yB);

  // pass 2: D_i = xd_i y_i + sum_{j<i} z[i][j] y_j  (b128 = 4 j x 2 samples; zero pads)
  float DA = xdA * yA, DB = xdB * yB;
  float dA1 = 0.f, dB1 = 0.f;
  {
    const int r3 = lane & 3;
    const int rsi = ((lane * (lane - 1)) >> 1) + 6 * (lane >> 2) +
                    ((r3 == 2) ? 3 : (r3 == 3) ? 5 : 0);
    const int cmax = (lane + 3) >> 2;
    const __bf16* zrow = zpair + rsi * 2;
#pragma unroll 4
    for (int c = 0; c < cmax; ++c) {
      const uint4 w = *(const uint4*)(zrow + c * 8);
      const float4 u0 = *(const float4*)(yp + c * 8);
      const float4 u1 = *(const float4*)(yp + c * 8 + 4);
      DA += bf_lo(w.x) * u0.x + bf_lo(w.z) * u1.x;
      dA1 += bf_lo(w.y) * u0.z + bf_lo(w.w) * u1.z;
      DB += bf_hi(w.x) * u0.y + bf_hi(w.z) * u1.y;
      dB1 += bf_hi(w.y) * u0.w + bf_hi(w.w) * u1.w;
    }
  }
  out[(size_t)(sb + s0) * 64 + lane] = DA + dA1;
  out[(size_t)(sb + s1) * 64 + lane] = DB + dB1;
}

// ---------------- launch ----------------
extern "C" void kernel_launch(void* const* d_in, const int* in_sizes, int n_in,
                              void* d_out, int out_size, void* d_ws, size_t ws_size,
                              hipStream_t stream) {
  const float* x   = (const float*)d_in[0];
  const float* Wd1 = (const float*)d_in[1];
  const float* bd1 = (const float*)d_in[2];
  const float* Wd2 = (const float*)d_in[3];
  const float* bd2 = (const float*)d_in[4];
  const float* Wdo = (const float*)d_in[5];
  const float* bdo = (const float*)d_in[6];
  const float* Wo1 = (const float*)d_in[7];
  const float* bo1 = (const float*)d_in[8];
  const float* Wo2 = (const float*)d_in[9];
  const float* bo2 = (const float*)d_in[10];
  const float* Woo = (const float*)d_in[11];
  const float* boo = (const float*)d_in[12];
  float* out = (float*)d_out;

  char* ws = (char*)d_ws;
  __bf16* W1b  = (__bf16*)(ws + 0);         //  65536 B (Wd1 rows 0-255, Wo1 rows 256-511)
  __bf16* Wd2b = (__bf16*)(ws + 65536);     // 131072 B
  __bf16* Wo2b = (__bf16*)(ws + 196608);    // 131072 B
  __bf16* Wdob = (__bf16*)(ws + 327680);    //  32768 B
  __bf16* Woob = (__bf16*)(ws + 360448);    // 1032192 B
  __bf16* g2   = (__bf16*)(ws + 1392640);   // B*256*2 = 16777216 B
  float*  xdp  = (float*)(ws + 18169856);   // B*64*4  =  8388608 B

  cast_all_kernel<<<512, 256, 0, stream>>>(
      Wd1, W1b, HDIM * NDIM,
      Wo1, W1b + HDIM * NDIM, HDIM * NDIM,
      Wd2, Wd2b, HDIM * HDIM,
      Wo2, Wo2b, HDIM * HDIM,
      Wdo, Wdob, NDIM * HDIM,
      Woo, Woob, OFFD * HDIM);

  trunk_kernel<<<B_TOT / 32, 512, 0, stream>>>(x, W1b, bd1, bo1, Wd2b, bd2, Wdob, bdo,
                                               Wo2b, bo2, g2, xdp);

  hipFuncSetAttribute((const void*)offdiag_apply_kernel,
                      hipFuncAttributeMaxDynamicSharedMemorySize, K2_SMEM);
  offdiag_apply_kernel<<<B_TOT / 32, 1024, K2_SMEM, stream>>>(g2, Woob, boo, xdp, x, out);
}